// Round 1
// 243.431 us; speedup vs baseline: 1.5248x; 1.5248x over previous
//
#include <hip/hip_runtime.h>

#define CCH 48       // channels
#define NPB 256      // nodes per bucket (1<<8); requires N <= 256*1024
#define MAXNB 1024   // max buckets the LDS histograms support

// --- k1: per-block LDS histograms over col-bucket and row-bucket, flush to global ---
__global__ void __launch_bounds__(256) bucket_count(const int* __restrict__ row,
                                                    const int* __restrict__ col,
                                                    int* __restrict__ colCnt,
                                                    int* __restrict__ rowCnt,
                                                    int NB, int E) {
    __shared__ int sc[MAXNB], sr[MAXNB];
    int tid = threadIdx.x;
    for (int i = tid; i < NB; i += 256) { sc[i] = 0; sr[i] = 0; }
    __syncthreads();
    int base = blockIdx.x * 2048;
    if (base + 2048 <= E) {
#pragma unroll
        for (int k = 0; k < 2; ++k) {
            int idx = base + (k * 256 + tid) * 4;
            int4 c = *reinterpret_cast<const int4*>(col + idx);
            int4 r = *reinterpret_cast<const int4*>(row + idx);
            atomicAdd(&sc[c.x >> 8], 1); atomicAdd(&sc[c.y >> 8], 1);
            atomicAdd(&sc[c.z >> 8], 1); atomicAdd(&sc[c.w >> 8], 1);
            atomicAdd(&sr[r.x >> 8], 1); atomicAdd(&sr[r.y >> 8], 1);
            atomicAdd(&sr[r.z >> 8], 1); atomicAdd(&sr[r.w >> 8], 1);
        }
    } else {
        for (int e = base + tid; e < E; e += 256) {
            atomicAdd(&sc[col[e] >> 8], 1);
            atomicAdd(&sr[row[e] >> 8], 1);
        }
    }
    __syncthreads();
    for (int i = tid; i < NB; i += 256) {
        if (sc[i]) atomicAdd(colCnt + i, sc[i]);
        if (sr[i]) atomicAdd(rowCnt + i, sr[i]);
    }
}

// --- k2: exclusive scan of both bucket-count arrays (NB <= 1024), init cursors ---
__global__ void __launch_bounds__(1024) bucket_scan(const int* __restrict__ colCnt,
                                                    const int* __restrict__ rowCnt,
                                                    int* __restrict__ colBase,
                                                    int* __restrict__ rowBase,
                                                    int* __restrict__ colCur,
                                                    int* __restrict__ rowCur,
                                                    int* __restrict__ ptrB,
                                                    int NB, int N, int E) {
    __shared__ int s[1024], s2[1024];
    int tid = threadIdx.x;
    int v = (tid < NB) ? colCnt[tid] : 0;
    int w = (tid < NB) ? rowCnt[tid] : 0;
    s[tid] = v; s2[tid] = w;
    __syncthreads();
    for (int off = 1; off < 1024; off <<= 1) {
        int a = (tid >= off) ? s[tid - off] : 0;
        int b = (tid >= off) ? s2[tid - off] : 0;
        __syncthreads();
        s[tid] += a; s2[tid] += b;
        __syncthreads();
    }
    if (tid < NB) {
        colBase[tid] = s[tid] - v;  colCur[tid] = s[tid] - v;
        rowBase[tid] = s2[tid] - w; rowCur[tid] = s2[tid] - w;
    }
    if (tid == 0) { colBase[NB] = E; rowBase[NB] = E; ptrB[N] = E; }
}

// --- k3: block-aggregated scatter into bucket regions ---
// col side: packed record  row | (col&255)<<24  (4B)  -> pairs[]
// row side: 1-byte record  row&255                    -> rbytes[]
__global__ void __launch_bounds__(256) bucket_scatter(const int* __restrict__ row,
                                                      const int* __restrict__ col,
                                                      int* __restrict__ colCur,
                                                      int* __restrict__ rowCur,
                                                      int* __restrict__ pairs,
                                                      unsigned char* __restrict__ rbytes,
                                                      int NB, int E) {
    __shared__ int sc[MAXNB], sr[MAXNB];
    int tid = threadIdx.x;
    for (int i = tid; i < NB; i += 256) { sc[i] = 0; sr[i] = 0; }
    __syncthreads();
    int base = blockIdx.x * 2048;
    int r[8], c[8];
    bool full = (base + 2048 <= E);
    if (full) {
#pragma unroll
        for (int k = 0; k < 2; ++k) {
            int idx = base + (k * 256 + tid) * 4;
            *reinterpret_cast<int4*>(&c[k * 4]) = *reinterpret_cast<const int4*>(col + idx);
            *reinterpret_cast<int4*>(&r[k * 4]) = *reinterpret_cast<const int4*>(row + idx);
        }
#pragma unroll
        for (int k = 0; k < 8; ++k) {
            atomicAdd(&sc[c[k] >> 8], 1);
            atomicAdd(&sr[r[k] >> 8], 1);
        }
    } else {
#pragma unroll
        for (int k = 0; k < 8; ++k) {
            int e = base + k * 256 + tid;
            if (e < E) {
                c[k] = col[e]; r[k] = row[e];
                atomicAdd(&sc[c[k] >> 8], 1);
                atomicAdd(&sr[r[k] >> 8], 1);
            } else {
                c[k] = -1;
            }
        }
    }
    __syncthreads();
    // reserve global ranges per (block, bucket); LDS slot becomes absolute cursor
    for (int i = tid; i < NB; i += 256) {
        int nc = sc[i];
        if (nc) sc[i] = atomicAdd(colCur + i, nc);
        int nr = sr[i];
        if (nr) sr[i] = atomicAdd(rowCur + i, nr);
    }
    __syncthreads();
    if (full) {
#pragma unroll
        for (int k = 0; k < 8; ++k) {
            int cc = c[k], rr = r[k];
            int p = atomicAdd(&sc[cc >> 8], 1);
            pairs[p] = rr | ((cc & 255) << 24);
            int q = atomicAdd(&sr[rr >> 8], 1);
            rbytes[q] = (unsigned char)(rr & 255);
        }
    } else {
#pragma unroll
        for (int k = 0; k < 8; ++k) {
            if (c[k] >= 0) {
                int cc = c[k], rr = r[k];
                int p = atomicAdd(&sc[cc >> 8], 1);
                pairs[p] = rr | ((cc & 255) << 24);
                int q = atomicAdd(&sr[rr >> 8], 1);
                rbytes[q] = (unsigned char)(rr & 255);
            }
        }
    }
}

// --- k4: per-bucket CSR build: LDS count -> LDS scan -> ptrB, then local scatter of srcA ---
__global__ void __launch_bounds__(256) bucket_csr(const int* __restrict__ pairs,
                                                  const int* __restrict__ colBase,
                                                  int* __restrict__ ptrB,
                                                  int* __restrict__ srcA, int N) {
    __shared__ int cnt[NPB], sc[NPB];
    int b = blockIdx.x, tid = threadIdx.x;
    int beg = colBase[b], end = colBase[b + 1];
    cnt[tid] = 0;
    __syncthreads();
    for (int i = beg + tid; i < end; i += 256)
        atomicAdd(&cnt[((unsigned)pairs[i]) >> 24], 1);
    __syncthreads();
    int v = cnt[tid];
    sc[tid] = v;
    __syncthreads();
    for (int off = 1; off < 256; off <<= 1) {
        int t = (tid >= off) ? sc[tid - off] : 0;
        __syncthreads();
        sc[tid] += t;
        __syncthreads();
    }
    int start = beg + sc[tid] - v;   // exclusive prefix
    int n = (b << 8) + tid;
    if (n < N) ptrB[n] = start;
    cnt[tid] = start;                // absolute cursor
    __syncthreads();
    for (int i = beg + tid; i < end; i += 256) {
        int pk = pairs[i];
        int p = atomicAdd(&cnt[((unsigned)pk) >> 24], 1);
        srcA[p] = pk & 0x00FFFFFF;
    }
}

// --- k5: per-bucket row-degree histogram -> dis = rsqrt(deg+1) ---
__global__ void __launch_bounds__(256) bucket_deg(const unsigned char* __restrict__ rbytes,
                                                  const int* __restrict__ rowBase,
                                                  float* __restrict__ dis, int N) {
    __shared__ int cnt[NPB];
    int b = blockIdx.x, tid = threadIdx.x;
    int beg = rowBase[b], end = rowBase[b + 1];
    cnt[tid] = 0;
    __syncthreads();
    for (int i = beg + tid; i < end; i += 256)
        atomicAdd(&cnt[rbytes[i]], 1);
    __syncthreads();
    int n = (b << 8) + tid;
    if (n < N) dis[n] = rsqrtf((float)cnt[tid] + 1.0f);
}

// --- Gather: 8 lanes/node, 6 channels/lane, 2-edge unrolled pipeline (unchanged) ---
__global__ void gather(const float* __restrict__ label,
                       const int* __restrict__ ptrB,
                       const int* __restrict__ srcA,
                       const float* __restrict__ dis,
                       float* __restrict__ out, int N) {
    int t = blockIdx.x * blockDim.x + threadIdx.x;
    int n = t >> 3;
    if (n >= N) return;
    int c0 = (t & 7) * 6;
    int beg = ptrB[n], end = ptrB[n + 1];
    float a0 = 0.f, a1 = 0.f, a2 = 0.f, a3 = 0.f, a4 = 0.f, a5 = 0.f;
    int i = beg;
    for (; i + 2 <= end; i += 2) {
        int s0 = srcA[i], s1 = srcA[i + 1];
        float w0 = dis[s0], w1 = dis[s1];
        const float* p0 = label + (long long)s0 * CCH + c0;
        const float* p1 = label + (long long)s1 * CCH + c0;
        float2 u0 = *reinterpret_cast<const float2*>(p0);
        float2 u1 = *reinterpret_cast<const float2*>(p0 + 2);
        float2 u2 = *reinterpret_cast<const float2*>(p0 + 4);
        float2 v0 = *reinterpret_cast<const float2*>(p1);
        float2 v1 = *reinterpret_cast<const float2*>(p1 + 2);
        float2 v2 = *reinterpret_cast<const float2*>(p1 + 4);
        a0 += w0 * u0.x; a1 += w0 * u0.y; a2 += w0 * u1.x;
        a3 += w0 * u1.y; a4 += w0 * u2.x; a5 += w0 * u2.y;
        a0 += w1 * v0.x; a1 += w1 * v0.y; a2 += w1 * v1.x;
        a3 += w1 * v1.y; a4 += w1 * v2.x; a5 += w1 * v2.y;
    }
    if (i < end) {
        int s0 = srcA[i];
        float w0 = dis[s0];
        const float* p0 = label + (long long)s0 * CCH + c0;
        float2 u0 = *reinterpret_cast<const float2*>(p0);
        float2 u1 = *reinterpret_cast<const float2*>(p0 + 2);
        float2 u2 = *reinterpret_cast<const float2*>(p0 + 4);
        a0 += w0 * u0.x; a1 += w0 * u0.y; a2 += w0 * u1.x;
        a3 += w0 * u1.y; a4 += w0 * u2.x; a5 += w0 * u2.y;
    }
    float dn = dis[n];
    const float* q = label + (long long)n * CCH + c0;
    float* o = out + (long long)n * CCH + c0;
    o[0] = dn * (a0 + dn * q[0]);
    o[1] = dn * (a1 + dn * q[1]);
    o[2] = dn * (a2 + dn * q[2]);
    o[3] = dn * (a3 + dn * q[3]);
    o[4] = dn * (a4 + dn * q[4]);
    o[5] = dn * (a5 + dn * q[5]);
}

extern "C" void kernel_launch(void* const* d_in, const int* in_sizes, int n_in,
                              void* d_out, int out_size, void* d_ws, size_t ws_size,
                              hipStream_t stream) {
    const float* label = (const float*)d_in[0];  // fp32 (N,48)
    const int* ei = (const int*)d_in[1];         // int32, (2,E) flat

    const int NC = in_sizes[0];  // N * 48
    const int N  = NC / CCH;
    const int E  = in_sizes[1] / 2;
    const int* row = ei;
    const int* col = ei + E;

    const int NB = (N + NPB - 1) / NPB;  // 391 buckets at N=100000

    // ws layout:
    // [colCnt NB][rowCnt NB][colBase NB+1][rowBase NB+1][colCur NB][rowCur NB]
    // [ptrB N+1][dis N f32][pairs E][rbytes E bytes][srcA E]
    int* colCnt  = (int*)d_ws;
    int* rowCnt  = colCnt + NB;
    int* colBase = rowCnt + NB;
    int* rowBase = colBase + NB + 1;
    int* colCur  = rowBase + NB + 1;
    int* rowCur  = colCur + NB;
    int* ptrB    = rowCur + NB;
    float* dis   = (float*)(ptrB + N + 1);
    int* pairs   = (int*)(dis + N);
    unsigned char* rbytes = (unsigned char*)(pairs + E);
    int* srcA    = (int*)(rbytes + (((size_t)E + 3) & ~(size_t)3));

    // only the two bucket-count arrays need zeroing (3 KB, was 12.8 MB)
    hipMemsetAsync(d_ws, 0, (size_t)(2 * NB) * sizeof(int), stream);

    int cblocks = (E + 2047) / 2048;
    bucket_count<<<cblocks, 256, 0, stream>>>(row, col, colCnt, rowCnt, NB, E);
    bucket_scan<<<1, 1024, 0, stream>>>(colCnt, rowCnt, colBase, rowBase,
                                        colCur, rowCur, ptrB, NB, N, E);
    bucket_scatter<<<cblocks, 256, 0, stream>>>(row, col, colCur, rowCur,
                                                pairs, rbytes, NB, E);
    bucket_csr<<<NB, 256, 0, stream>>>(pairs, colBase, ptrB, srcA, N);
    bucket_deg<<<NB, 256, 0, stream>>>(rbytes, rowBase, dis, N);

    int tg = N * 8;
    gather<<<(tg + 255) / 256, 256, 0, stream>>>(label, ptrB, srcA, dis,
                                                 (float*)d_out, N);
}

// Round 2
// 165.650 us; speedup vs baseline: 2.2407x; 1.4696x over previous
//
#include <hip/hip_runtime.h>
#include <hip/hip_fp16.h>

#define CCH 48       // channels
#define NPB 256      // nodes per bucket (1<<8); requires N <= 256*1024
#define MAXNB 1024   // max buckets the LDS histograms support
#define SCAT_EPB 4096  // edges per scatter block (256 thr x 16)

// --- k1: block-aggregated scatter into fixed-capacity bucket regions ---
// col side: packed record  row | (col&255)<<24  (4B)  -> pairs[b*CAP + ...]
// row side: 1-byte record  row&255                    -> rbytes[b*CAP + ...]
__global__ void __launch_bounds__(256) bucket_scatter(const int* __restrict__ row,
                                                      const int* __restrict__ col,
                                                      int* __restrict__ colCur,
                                                      int* __restrict__ rowCur,
                                                      int* __restrict__ pairs,
                                                      unsigned char* __restrict__ rbytes,
                                                      int NB, int E, int CAP) {
    __shared__ int sc[MAXNB], sr[MAXNB];
    int tid = threadIdx.x;
    for (int i = tid; i < NB; i += 256) { sc[i] = 0; sr[i] = 0; }
    __syncthreads();
    int base = blockIdx.x * SCAT_EPB;
    int r[16], c[16];
    bool full = (base + SCAT_EPB <= E);
    if (full) {
#pragma unroll
        for (int k = 0; k < 4; ++k) {
            int idx = base + (k * 256 + tid) * 4;
            *reinterpret_cast<int4*>(&c[k * 4]) = *reinterpret_cast<const int4*>(col + idx);
            *reinterpret_cast<int4*>(&r[k * 4]) = *reinterpret_cast<const int4*>(row + idx);
        }
#pragma unroll
        for (int k = 0; k < 16; ++k) {
            atomicAdd(&sc[c[k] >> 8], 1);
            atomicAdd(&sr[r[k] >> 8], 1);
        }
    } else {
#pragma unroll
        for (int k = 0; k < 16; ++k) {
            int e = base + k * 256 + tid;
            if (e < E) {
                c[k] = col[e]; r[k] = row[e];
                atomicAdd(&sc[c[k] >> 8], 1);
                atomicAdd(&sr[r[k] >> 8], 1);
            } else {
                c[k] = -1;
            }
        }
    }
    __syncthreads();
    // reserve ranges: one global atomic per (block,bucket); LDS slot -> absolute cursor
    for (int i = tid; i < NB; i += 256) {
        int nc = sc[i];
        if (nc) sc[i] = i * CAP + atomicAdd(colCur + i, nc);
        int nr = sr[i];
        if (nr) sr[i] = i * CAP + atomicAdd(rowCur + i, nr);
    }
    __syncthreads();
    if (full) {
#pragma unroll
        for (int k = 0; k < 16; ++k) {
            int cc = c[k], rr = r[k];
            int p = atomicAdd(&sc[cc >> 8], 1);
            pairs[p] = rr | ((cc & 255) << 24);
            int q = atomicAdd(&sr[rr >> 8], 1);
            rbytes[q] = (unsigned char)(rr & 255);
        }
    } else {
#pragma unroll
        for (int k = 0; k < 16; ++k) {
            if (c[k] >= 0) {
                int cc = c[k], rr = r[k];
                int p = atomicAdd(&sc[cc >> 8], 1);
                pairs[p] = rr | ((cc & 255) << 24);
                int q = atomicAdd(&sr[rr >> 8], 1);
                rbytes[q] = (unsigned char)(rr & 255);
            }
        }
    }
}

// --- k2: per-bucket CSR build (in-place via LDS stage) + row-degree -> dis ---
__global__ void __launch_bounds__(256) bucket_csr_deg(int* __restrict__ pairs,
                                                      const int* __restrict__ colCur,
                                                      const unsigned char* __restrict__ rbytes,
                                                      const int* __restrict__ rowCur,
                                                      int2* __restrict__ ptr2,
                                                      float* __restrict__ dis,
                                                      int N, int CAP) {
    extern __shared__ int stage[];  // CAP ints
    __shared__ int cnt[NPB], sc[NPB];
    int b = blockIdx.x, tid = threadIdx.x;
    int beg = b * CAP;
    int cnum = colCur[b];
    cnt[tid] = 0;
    __syncthreads();
    // load pairs into LDS stage + per-node histogram
    int nq = cnum >> 2;
    for (int q = tid; q < nq; q += 256) {
        int4 pk = *reinterpret_cast<const int4*>(pairs + beg + q * 4);
        *reinterpret_cast<int4*>(stage + q * 4) = pk;
        atomicAdd(&cnt[((unsigned)pk.x) >> 24], 1);
        atomicAdd(&cnt[((unsigned)pk.y) >> 24], 1);
        atomicAdd(&cnt[((unsigned)pk.z) >> 24], 1);
        atomicAdd(&cnt[((unsigned)pk.w) >> 24], 1);
    }
    for (int i = (nq << 2) + tid; i < cnum; i += 256) {
        int pk = pairs[beg + i];
        stage[i] = pk;
        atomicAdd(&cnt[((unsigned)pk) >> 24], 1);
    }
    __syncthreads();
    int v = cnt[tid];
    sc[tid] = v;
    __syncthreads();
    for (int off = 1; off < 256; off <<= 1) {
        int t = (tid >= off) ? sc[tid - off] : 0;
        __syncthreads();
        sc[tid] += t;
        __syncthreads();
    }
    int start = beg + sc[tid] - v;  // exclusive prefix, absolute
    int n = (b << 8) + tid;
    if (n < N) ptr2[n] = make_int2(start, start + v);
    cnt[tid] = start;  // absolute cursor
    __syncthreads();
    // scatter src ids back over the same region (stage holds the originals)
    for (int i = tid; i < cnum; i += 256) {
        int pk = stage[i];
        int p = atomicAdd(&cnt[((unsigned)pk) >> 24], 1);
        pairs[p] = pk & 0x00FFFFFF;
    }
    // --- row side: degree histogram -> dis ---
    __syncthreads();
    cnt[tid] = 0;
    __syncthreads();
    int rnum = rowCur[b];
    int nq4 = rnum >> 2;
    for (int q = tid; q < nq4; q += 256) {
        uchar4 u = *reinterpret_cast<const uchar4*>(rbytes + beg + q * 4);
        atomicAdd(&cnt[u.x], 1);
        atomicAdd(&cnt[u.y], 1);
        atomicAdd(&cnt[u.z], 1);
        atomicAdd(&cnt[u.w], 1);
    }
    for (int i = (nq4 << 2) + tid; i < rnum; i += 256)
        atomicAdd(&cnt[rbytes[beg + i]], 1);
    __syncthreads();
    if (n < N) dis[n] = rsqrtf((float)cnt[tid] + 1.0f);
}

// --- k3: lab16[n,c] = (half)(dis[n] * label[n,c]) ; 8 floats/thread ---
__global__ void __launch_bounds__(256) convert_scale(const float* __restrict__ label,
                                                     const float* __restrict__ dis,
                                                     __half* __restrict__ lab16,
                                                     int total) {  // total = N*48, mult of 8
    int t = blockIdx.x * blockDim.x + threadIdx.x;
    int i0 = t * 8;
    if (i0 >= total) return;
    int n = t / 6;  // 48/8 = 6 threads per row
    float w = dis[n];
    float4 a = *reinterpret_cast<const float4*>(label + i0);
    float4 bq = *reinterpret_cast<const float4*>(label + i0 + 4);
    union { __half2 h[4]; uint4 u; } pk;
    pk.h[0] = __floats2half2_rn(w * a.x, w * a.y);
    pk.h[1] = __floats2half2_rn(w * a.z, w * a.w);
    pk.h[2] = __floats2half2_rn(w * bq.x, w * bq.y);
    pk.h[3] = __floats2half2_rn(w * bq.z, w * bq.w);
    *reinterpret_cast<uint4*>(lab16 + i0) = pk.u;
}

// --- k4: gather over fp16 pre-scaled rows; 8 lanes/node, 6 ch/lane, 4-edge unroll ---
// out[n,c] = dis[n] * ( sum_{e: col=n} lab16[src,c] + lab16[n,c] )
__global__ void __launch_bounds__(256) gather16(const __half* __restrict__ lab16,
                                                const int2* __restrict__ ptr2,
                                                const int* __restrict__ srcA,
                                                const float* __restrict__ dis,
                                                float* __restrict__ out, int N) {
    int t = blockIdx.x * blockDim.x + threadIdx.x;
    int n = t >> 3;
    if (n >= N) return;
    int c0 = (t & 7) * 6;
    int2 be = ptr2[n];
    float a0 = 0.f, a1 = 0.f, a2 = 0.f, a3 = 0.f, a4 = 0.f, a5 = 0.f;
    int i = be.x, end = be.y;
    for (; i + 4 <= end; i += 4) {
        int s0 = srcA[i], s1 = srcA[i + 1], s2 = srcA[i + 2], s3 = srcA[i + 3];
        const __half2* p0 = reinterpret_cast<const __half2*>(lab16 + s0 * CCH + c0);
        const __half2* p1 = reinterpret_cast<const __half2*>(lab16 + s1 * CCH + c0);
        const __half2* p2 = reinterpret_cast<const __half2*>(lab16 + s2 * CCH + c0);
        const __half2* p3 = reinterpret_cast<const __half2*>(lab16 + s3 * CCH + c0);
        __half2 x0 = p0[0], x1 = p0[1], x2 = p0[2];
        __half2 y0 = p1[0], y1 = p1[1], y2 = p1[2];
        __half2 z0 = p2[0], z1 = p2[1], z2 = p2[2];
        __half2 w0 = p3[0], w1 = p3[1], w2 = p3[2];
        float2 f;
        f = __half22float2(x0); a0 += f.x; a1 += f.y;
        f = __half22float2(x1); a2 += f.x; a3 += f.y;
        f = __half22float2(x2); a4 += f.x; a5 += f.y;
        f = __half22float2(y0); a0 += f.x; a1 += f.y;
        f = __half22float2(y1); a2 += f.x; a3 += f.y;
        f = __half22float2(y2); a4 += f.x; a5 += f.y;
        f = __half22float2(z0); a0 += f.x; a1 += f.y;
        f = __half22float2(z1); a2 += f.x; a3 += f.y;
        f = __half22float2(z2); a4 += f.x; a5 += f.y;
        f = __half22float2(w0); a0 += f.x; a1 += f.y;
        f = __half22float2(w1); a2 += f.x; a3 += f.y;
        f = __half22float2(w2); a4 += f.x; a5 += f.y;
    }
    for (; i < end; ++i) {
        int s0 = srcA[i];
        const __half2* p0 = reinterpret_cast<const __half2*>(lab16 + s0 * CCH + c0);
        __half2 x0 = p0[0], x1 = p0[1], x2 = p0[2];
        float2 f;
        f = __half22float2(x0); a0 += f.x; a1 += f.y;
        f = __half22float2(x1); a2 += f.x; a3 += f.y;
        f = __half22float2(x2); a4 += f.x; a5 += f.y;
    }
    // self loop: lab16[n] is already dis[n]*label[n]
    {
        const __half2* ps = reinterpret_cast<const __half2*>(lab16 + n * CCH + c0);
        __half2 x0 = ps[0], x1 = ps[1], x2 = ps[2];
        float2 f;
        f = __half22float2(x0); a0 += f.x; a1 += f.y;
        f = __half22float2(x1); a2 += f.x; a3 += f.y;
        f = __half22float2(x2); a4 += f.x; a5 += f.y;
    }
    float dn = dis[n];
    float* o = out + n * CCH + c0;
    o[0] = dn * a0; o[1] = dn * a1; o[2] = dn * a2;
    o[3] = dn * a3; o[4] = dn * a4; o[5] = dn * a5;
}

extern "C" void kernel_launch(void* const* d_in, const int* in_sizes, int n_in,
                              void* d_out, int out_size, void* d_ws, size_t ws_size,
                              hipStream_t stream) {
    const float* label = (const float*)d_in[0];  // fp32 (N,48)
    const int* ei = (const int*)d_in[1];         // int32, (2,E) flat

    const int NC = in_sizes[0];  // N * 48
    const int N  = NC / CCH;
    const int E  = in_sizes[1] / 2;
    const int* row = ei;
    const int* col = ei + E;

    const int NB = (N + NPB - 1) / NPB;  // 391 buckets at N=100000
    const int avg = (E + NB - 1) / NB;   // ~4093
    int slack = avg / 4; if (slack < 768) slack = 768;
    const int CAP = (avg + slack + 15) & ~15;  // fixed bucket capacity (~16 sigma slack)

    // ws layout (16B-aligned sections):
    // [pairs NB*CAP int] [ptr2 N int2] [dis N f32] [colCur NB][rowCur NB] [pad]
    // [rbytes NB*CAP bytes] [lab16 N*48 half]
    int* pairs = (int*)d_ws;
    int2* ptr2 = (int2*)(pairs + (size_t)NB * CAP);
    float* dis = (float*)(ptr2 + N);
    int* colCur = (int*)(dis + N);
    int* rowCur = colCur + NB;
    size_t rb_off = (((size_t)(rowCur + NB) - (size_t)d_ws) + 15) & ~(size_t)15;
    unsigned char* rbytes = (unsigned char*)d_ws + rb_off;
    __half* lab16 = (__half*)(rbytes + (size_t)NB * CAP);

    // zero the two cursor arrays (~3 KB)
    hipMemsetAsync(colCur, 0, (size_t)(2 * NB) * sizeof(int), stream);

    int sblocks = (E + SCAT_EPB - 1) / SCAT_EPB;
    bucket_scatter<<<sblocks, 256, 0, stream>>>(row, col, colCur, rowCur,
                                                pairs, rbytes, NB, E, CAP);
    bucket_csr_deg<<<NB, 256, (size_t)CAP * sizeof(int), stream>>>(
        pairs, colCur, rbytes, rowCur, ptr2, dis, N, CAP);

    int total = N * CCH;
    convert_scale<<<(total / 8 + 255) / 256, 256, 0, stream>>>(label, dis, lab16, total);

    int tg = N * 8;
    gather16<<<(tg + 255) / 256, 256, 0, stream>>>(lab16, ptr2, pairs /*srcA in-place*/,
                                                   dis, (float*)d_out, N);
}